// Round 2
// baseline (1638.064 us; speedup 1.0000x reference)
//
#include <hip/hip_runtime.h>

typedef unsigned long long u64;
typedef unsigned int u32;

#define MAXN 8704            // 8700 rounded to 64
#define CHUNK 512            // j-chunk for rank kernel

// ---------------- K0: merge + clip + cxcywh->xyxy + sort key ----------------
__global__ void prep_kernel(const float* __restrict__ yb, const float* __restrict__ yc,
                            const float* __restrict__ db, const float* __restrict__ dc,
                            int n1, int n,
                            float4* __restrict__ xyxy, float* __restrict__ conf,
                            u32* __restrict__ key) {
    int i = blockIdx.x * 256 + threadIdx.x;
    if (i >= n) return;
    float cx, cy, w, h, c;
    if (i < n1) {
        const float* b = yb + (size_t)i * 4;
        cx = b[0]; cy = b[1]; w = b[2]; h = b[3]; c = yc[i];
    } else {
        const float* b = db + (size_t)(i - n1) * 4;
        cx = b[0]; cy = b[1]; w = b[2]; h = b[3]; c = dc[i - n1];
    }
    c = fminf(fmaxf(c, 0.0f), 1.0f);
    float hw = w * 0.5f, hh = h * 0.5f;
    xyxy[i] = make_float4(cx - hw, cy - hh, cx + hw, cy + hh);
    conf[i] = c;
    key[i]  = __float_as_uint(c);
}

// ---------------- K1: O(N^2) stable rank ------------------------------------
__global__ void rank_kernel(const u32* __restrict__ key, int n, int* __restrict__ rank) {
    __shared__ __align__(16) u32 sk[CHUNK];
    int t = threadIdx.x;
    int jbase = blockIdx.y * CHUNK;
    for (int s = t; s < CHUNK; s += 256) {
        int j = jbase + s;
        sk[s] = (j < n) ? key[j] : 0u;
    }
    __syncthreads();
    int i = blockIdx.x * 256 + t;
    if (i >= n) return;
    u32 ki = key[i];
    int cnt = 0;
    const uint4* sk4 = (const uint4*)sk;
    for (int s = 0; s < CHUNK / 4; ++s) {
        uint4 k = sk4[s];
        int j = jbase + s * 4;
        cnt += (k.x > ki) || (k.x == ki && (j + 0) < i);
        cnt += (k.y > ki) || (k.y == ki && (j + 1) < i);
        cnt += (k.z > ki) || (k.z == ki && (j + 2) < i);
        cnt += (k.w > ki) || (k.w == ki && (j + 3) < i);
    }
    if (cnt) atomicAdd(&rank[i], cnt);
}

// ---------------- K2: scatter into sorted order -----------------------------
__global__ void scatter_kernel(const float4* __restrict__ xyxy, const float* __restrict__ conf,
                               const int* __restrict__ rank, int n,
                               float4* __restrict__ sbox, float* __restrict__ sconf) {
    int i = blockIdx.x * 256 + threadIdx.x;
    if (i >= n) return;
    int r = rank[i];
    sbox[r]  = xyxy[i];
    sconf[r] = conf[i];
}

// ---------------- K3: suppression bit-matrix (upper triangle) ---------------
__global__ void iou_kernel(const float4* __restrict__ sbox, int n, int nw,
                           u64* __restrict__ sup) {
    int bi = blockIdx.y, bj = blockIdx.x;
    if (bj < bi) return;
    __shared__ float4 cb[64];
    int t  = threadIdx.x;
    int j0 = bj * 64;
    int jt = j0 + t;
    cb[t] = (jt < n) ? sbox[jt] : make_float4(0, 0, 0, 0);
    __syncthreads();
    int i = bi * 64 + t;
    if (i >= n) return;
    float4 a = sbox[i];
    float areaA = (a.z - a.x) * (a.w - a.y);
    u64 word = 0;
    int kmax = min(64, n - j0);
    for (int k = 0; k < kmax; ++k) {
        int j = j0 + k;
        float4 b = cb[k];
        float iw = fmaxf(fminf(a.z, b.z) - fmaxf(a.x, b.x), 0.0f);
        float ih = fmaxf(fminf(a.w, b.w) - fmaxf(a.y, b.y), 0.0f);
        float inter = iw * ih;
        float areaB = (b.z - b.x) * (b.w - b.y);
        float uni = areaA + areaB - inter;
        float iou = inter / fmaxf(uni, 1e-9f);
        if (j > i && iou > 0.5f) word |= (1ULL << k);
    }
    sup[(size_t)i * nw + bj] = word;
}

// ---------------- K4: pipelined greedy scan, 128 rows/round -----------------
// Thread t<nw owns remv word t (accumulated in a register with 1 round of
// slack). Diag block and the two "next" remv words are prefetched
// speculatively at round start (static addresses), so the only serial chain
// is the 128-step in-block resolve on wave 0 (ALU-only, LDS reads hoisted).
__global__ __launch_bounds__(256) void scan_kernel(const u64* __restrict__ sup, int n, int nw,
                                                   u64* __restrict__ keepw) {
    __shared__ __align__(16) ulonglong2 sdA[2][64];  // rows 0..63 of block: {word 2b, word 2b+1}
    __shared__ __align__(16) ulonglong2 sdB[2][32];  // rows 64..127: word 2b+1, packed 2 rows/entry
    __shared__ __align__(16) u64 s_remv[2][2];
    __shared__ u64 s_kw[2][2];
    int t = threadIdx.x;
    int B = (n + 127) / 128;
    u64 remv_reg = 0;

    // ---- prologue: zero state, stage diag block 0 ----
    if (t == 0) {
        s_remv[0][0] = 0; s_remv[0][1] = 0;
        s_kw[0][0] = 0; s_kw[0][1] = 0; s_kw[1][0] = 0; s_kw[1][1] = 0;
    }
    if (t < 128) {
        u64 d0 = 0, d1 = 0;
        if (t < n) {
            if (t < 64) d0 = sup[(size_t)t * nw + 0];
            if (nw > 1) d1 = sup[(size_t)t * nw + 1];
        }
        if (t < 64) sdA[0][t] = make_ulonglong2(d0, d1);
        else {
            // two threads write halves of one ulonglong2 entry: use u64 view
            ((u64*)&sdB[0][0])[t - 64] = d1;
        }
    }
    __syncthreads();

    int c = 0;
    for (int b = 0; b < B; ++b) {
        int w0 = 2 * b + 2, w1 = 2 * b + 3;

        // ---- phase 0: issue all loads, then resolve (wave 0) ----
        if (t == 255) { s_remv[c ^ 1][0] = 0; s_remv[c ^ 1][1] = 0; }

        u64 sv0 = 0, sv1 = 0, nd0 = 0, nd1 = 0;
        if (t < 128) {
            int r = b * 128 + t;                 // speculative: block-b rows, next words
            if (r < n) {
                if (w0 < nw) sv0 = sup[(size_t)r * nw + w0];
                if (w1 < nw) sv1 = sup[(size_t)r * nw + w1];
            }
            int rn = (b + 1) * 128 + t;          // next diag block
            if (b + 1 < B && rn < n) {
                if (t < 64) nd0 = sup[(size_t)rn * nw + w0];
                if (w1 < nw) nd1 = sup[(size_t)rn * nw + w1];
            }
        }

        // owner loads: fold kw_{b-1} rows into remv_reg (1 round of slack)
        u64 kp0 = s_kw[(b & 1) ^ 1][0];
        u64 kp1 = s_kw[(b & 1) ^ 1][1];
        if (t >= w0 && t < nw) {
            int rbase = (b - 1) * 128;
            u64 m = kp0;
            while (m) { int k = __ffsll(m) - 1; m &= m - 1;
                        remv_reg |= sup[(size_t)(rbase + k) * nw + t]; }
            m = kp1;
            while (m) { int k = __ffsll(m) - 1; m &= m - 1;
                        remv_reg |= sup[(size_t)(rbase + 64 + k) * nw + t]; }
        }

        // resolve: serial 128-step chain, all of wave 0 redundantly (uniform)
        if (t < 64) {
            u64 c0 = s_remv[c][0], c1 = s_remv[c][1];
            u64 kw0 = 0, kw1 = 0;
            int lim = n - b * 128;               // >0; >=128 except last block
            #pragma unroll
            for (int g = 0; g < 8; ++g) {
                ulonglong2 r[8];
                #pragma unroll
                for (int j = 0; j < 8; ++j) r[j] = sdA[c][g * 8 + j];   // hoisted, static
                #pragma unroll
                for (int j = 0; j < 8; ++j) {
                    int k = g * 8 + j;
                    if (k < lim && !((c0 >> k) & 1)) {
                        kw0 |= 1ULL << k;
                        c0 |= r[j].x;
                        c1 |= r[j].y;
                    }
                }
            }
            #pragma unroll
            for (int g = 0; g < 4; ++g) {
                ulonglong2 r[8];
                #pragma unroll
                for (int j = 0; j < 8; ++j) r[j] = sdB[c][g * 8 + j];   // 2 rows per entry
                #pragma unroll
                for (int j = 0; j < 16; ++j) {
                    int k = g * 16 + j;
                    u64 d = (j & 1) ? r[j >> 1].y : r[j >> 1].x;
                    if (k + 64 < lim && !((c1 >> k) & 1)) {
                        kw1 |= 1ULL << k;
                        c1 |= d;
                    }
                }
            }
            if (t == 0) {
                s_kw[b & 1][0] = kw0; s_kw[b & 1][1] = kw1;
                keepw[2 * b] = kw0;
                if (2 * b + 1 < nw) keepw[2 * b + 1] = kw1;
            }
        }
        __syncthreads();

        // ---- phase 1: combine speculative data + owner words, stage next diag
        u64 kwb0 = s_kw[b & 1][0], kwb1 = s_kw[b & 1][1];
        if (t < 128) {
            bool kept = (t < 64) ? ((kwb0 >> t) & 1) : ((kwb1 >> (t - 64)) & 1);
            if (kept) {
                if (sv0) atomicOr(&s_remv[c ^ 1][0], sv0);
                if (sv1) atomicOr(&s_remv[c ^ 1][1], sv1);
            }
            if (t < 64) sdA[c ^ 1][t] = make_ulonglong2(nd0, nd1);
            else        ((u64*)&sdB[c ^ 1][0])[t - 64] = nd1;
        }
        if (t == w0 && t < nw) atomicOr(&s_remv[c ^ 1][0], remv_reg);
        if (t == w1 && t < nw) atomicOr(&s_remv[c ^ 1][1], remv_reg);
        __syncthreads();
        c ^= 1;
    }
}

// ---------------- K5: masked output -----------------------------------------
__global__ void out_kernel(const float* __restrict__ sbox, const float* __restrict__ sconf,
                           const u64* __restrict__ keepw, int n, float* __restrict__ out) {
    int e = blockIdx.x * 256 + threadIdx.x;
    if (e >= n * 5) return;
    int r = e / 5, c = e - r * 5;
    float keep = ((keepw[r >> 6] >> (r & 63)) & 1ULL) ? 1.0f : 0.0f;
    float v = (c < 4) ? sbox[r * 4 + c] : sconf[r];
    out[e] = v * keep;
}

extern "C" void kernel_launch(void* const* d_in, const int* in_sizes, int n_in,
                              void* d_out, int out_size, void* d_ws, size_t ws_size,
                              hipStream_t stream) {
    const float* yb = (const float*)d_in[0];
    const float* yc = (const float*)d_in[1];
    const float* db = (const float*)d_in[2];
    const float* dc = (const float*)d_in[3];
    int n1 = in_sizes[1];
    int n2 = in_sizes[3];
    int n  = n1 + n2;                          // 8700
    int nw = (n + 63) / 64;                    // 136

    char* w = (char*)d_ws;
    u64*    sup   = (u64*)w;                                   // MAXN*NW*8
    float4* xyxy  = (float4*)(w + (size_t)MAXN * nw * 8);
    float4* sbox  = xyxy + MAXN;
    float*  conf  = (float*)(sbox + MAXN);
    float*  sconf = conf + MAXN;
    u32*    key   = (u32*)(sconf + MAXN);
    int*    rank  = (int*)(key + MAXN);
    u64*    keepw = (u64*)(rank + MAXN);

    hipMemsetAsync(rank, 0, MAXN * sizeof(int), stream);

    int nb = (n + 255) / 256;                                  // 34
    prep_kernel<<<nb, 256, 0, stream>>>(yb, yc, db, dc, n1, n, xyxy, conf, key);

    dim3 g1(nb, (n + CHUNK - 1) / CHUNK);                      // 34 x 17
    rank_kernel<<<g1, 256, 0, stream>>>(key, n, rank);

    scatter_kernel<<<nb, 256, 0, stream>>>(xyxy, conf, rank, n, sbox, sconf);

    dim3 g3(nw, nw);                                           // 136 x 136
    iou_kernel<<<g3, 64, 0, stream>>>(sbox, n, nw, sup);

    scan_kernel<<<1, 256, 0, stream>>>(sup, n, nw, keepw);

    out_kernel<<<(n * 5 + 255) / 256, 256, 0, stream>>>((const float*)sbox, sconf,
                                                        keepw, n, (float*)d_out);
}

// Round 3
// 498.490 us; speedup vs baseline: 3.2861x; 3.2861x over previous
//
#include <hip/hip_runtime.h>

typedef unsigned long long u64;
typedef unsigned int u32;

#define MAXN 8704            // 8700 rounded to 64
#define CHUNK 512            // j-chunk for rank kernel

__device__ inline u64 shfl_xor_u64(u64 v, int m) {
    u32 lo = (u32)v, hi = (u32)(v >> 32);
    lo = (u32)__shfl_xor((int)lo, m, 64);
    hi = (u32)__shfl_xor((int)hi, m, 64);
    return ((u64)hi << 32) | lo;
}

// ---------------- K0: merge + clip + cxcywh->xyxy + sort key ----------------
__global__ void prep_kernel(const float* __restrict__ yb, const float* __restrict__ yc,
                            const float* __restrict__ db, const float* __restrict__ dc,
                            int n1, int n,
                            float4* __restrict__ xyxy, float* __restrict__ conf,
                            u32* __restrict__ key) {
    int i = blockIdx.x * 256 + threadIdx.x;
    if (i >= n) return;
    float cx, cy, w, h, c;
    if (i < n1) {
        const float* b = yb + (size_t)i * 4;
        cx = b[0]; cy = b[1]; w = b[2]; h = b[3]; c = yc[i];
    } else {
        const float* b = db + (size_t)(i - n1) * 4;
        cx = b[0]; cy = b[1]; w = b[2]; h = b[3]; c = dc[i - n1];
    }
    c = fminf(fmaxf(c, 0.0f), 1.0f);
    float hw = w * 0.5f, hh = h * 0.5f;
    xyxy[i] = make_float4(cx - hw, cy - hh, cx + hw, cy + hh);
    conf[i] = c;
    key[i]  = __float_as_uint(c);
}

// ---------------- K1: O(N^2) stable rank ------------------------------------
__global__ void rank_kernel(const u32* __restrict__ key, int n, int* __restrict__ rank) {
    __shared__ __align__(16) u32 sk[CHUNK];
    int t = threadIdx.x;
    int jbase = blockIdx.y * CHUNK;
    for (int s = t; s < CHUNK; s += 256) {
        int j = jbase + s;
        sk[s] = (j < n) ? key[j] : 0u;
    }
    __syncthreads();
    int i = blockIdx.x * 256 + t;
    if (i >= n) return;
    u32 ki = key[i];
    int cnt = 0;
    const uint4* sk4 = (const uint4*)sk;
    for (int s = 0; s < CHUNK / 4; ++s) {
        uint4 k = sk4[s];
        int j = jbase + s * 4;
        cnt += (k.x > ki) || (k.x == ki && (j + 0) < i);
        cnt += (k.y > ki) || (k.y == ki && (j + 1) < i);
        cnt += (k.z > ki) || (k.z == ki && (j + 2) < i);
        cnt += (k.w > ki) || (k.w == ki && (j + 3) < i);
    }
    if (cnt) atomicAdd(&rank[i], cnt);
}

// ---------------- K2: scatter into sorted order -----------------------------
__global__ void scatter_kernel(const float4* __restrict__ xyxy, const float* __restrict__ conf,
                               const int* __restrict__ rank, int n,
                               float4* __restrict__ sbox, float* __restrict__ sconf) {
    int i = blockIdx.x * 256 + threadIdx.x;
    if (i >= n) return;
    int r = rank[i];
    sbox[r]  = xyxy[i];
    sconf[r] = conf[i];
}

// ---------------- K3: suppression bit-matrix + compact band -----------------
// band[r][s] = sup[r][2*(r/128) + s], s in 0..3 (zero elsewhere, pre-memset)
__global__ void iou_kernel(const float4* __restrict__ sbox, int n, int nw,
                           u64* __restrict__ sup, u64* __restrict__ band) {
    int bi = blockIdx.y, bj = blockIdx.x;
    if (bj < bi) return;
    __shared__ float4 cb[64];
    int t  = threadIdx.x;
    int j0 = bj * 64;
    int jt = j0 + t;
    cb[t] = (jt < n) ? sbox[jt] : make_float4(0, 0, 0, 0);
    __syncthreads();
    int i = bi * 64 + t;
    if (i >= n) return;
    float4 a = sbox[i];
    float areaA = (a.z - a.x) * (a.w - a.y);
    u64 word = 0;
    int kmax = min(64, n - j0);
    for (int k = 0; k < kmax; ++k) {
        int j = j0 + k;
        float4 b = cb[k];
        float iw = fmaxf(fminf(a.z, b.z) - fmaxf(a.x, b.x), 0.0f);
        float ih = fmaxf(fminf(a.w, b.w) - fmaxf(a.y, b.y), 0.0f);
        float inter = iw * ih;
        float areaB = (b.z - b.x) * (b.w - b.y);
        float uni = areaA + areaB - inter;
        float iou = inter / fmaxf(uni, 1e-9f);
        if (j > i && iou > 0.5f) word |= (1ULL << k);
    }
    sup[(size_t)i * nw + bj] = word;
    int slot = bj - (bi & ~1);               // 2*(i/128) == (bi & ~1)
    if (slot >= 0 && slot < 4) band[(size_t)i * 4 + slot] = word;
}

// ---------------- K4: pipelined greedy scan, 128 rows/round -----------------
// Per round b: wave 0 resolves block b (serial 128-step chain on LDS-staged
// diag); waves 1-3 CONCURRENTLY gather prev round's kept rows into future
// remv words (one word per thread, 16-deep pipelined loads -> vmcnt(16));
// near words (2b+2,2b+3) come from speculative band loads + wave OR-reduce.
__global__ __launch_bounds__(256) void scan_kernel(const u64* __restrict__ sup,
                                                   const u64* __restrict__ band,
                                                   int n, int nw,
                                                   u64* __restrict__ keepw) {
    __shared__ u64 s_remv[144];
    __shared__ __align__(16) ulonglong2 sdA[2][64];   // rows 0..63: words 2b,2b+1
    __shared__ u64 sdB[2][64];                        // rows 64..127: word 2b+1
    __shared__ int s_list[160];                       // kept rows of prev round (padded)
    __shared__ int s_cnt;
    __shared__ u64 s_kw[2];

    int t = threadIdx.x;
    int B = (n + 127) / 128;

    // ---- prologue ----
    for (int i = t; i < 144; i += 256) s_remv[i] = 0;
    if (t == 0) s_cnt = 0;
    if (t < 128) {
        if (t < 64) sdA[0][t] = make_ulonglong2(band[(size_t)t * 4 + 0], band[(size_t)t * 4 + 1]);
        else        sdB[0][t - 64] = band[(size_t)t * 4 + 1];
    }
    __syncthreads();

    for (int b = 0; b < B; ++b) {
        int c = b & 1;
        // ================= phase 0 =================
        // speculative band loads (near words of block b, diag of block b+1)
        u64 sv0 = 0, sv1 = 0, nd0 = 0, nd1 = 0;
        if (t < 128) {
            int r = b * 128 + t;
            if (r < n) { sv0 = band[(size_t)r * 4 + 2]; sv1 = band[(size_t)r * 4 + 3]; }
            int rn = r + 128;
            if (rn < n) {
                if (t < 64) nd0 = band[(size_t)rn * 4 + 0];
                nd1 = band[(size_t)rn * 4 + 1];
            }
        }

        // far-gather: waves 1..3, prev kept list, words >= 2b+2
        int cntP = s_cnt;
        int w = 2 * b + 2 + (t - 64);
        if (t >= 64 && cntP > 0 && w < nw) {
            int cp = (cntP + 15) & ~15;
            const u64* __restrict__ colp = sup + w;
            int ra[16];
            u64 v0[16];
            #pragma unroll
            for (int j = 0; j < 16; ++j) ra[j] = s_list[j];
            #pragma unroll
            for (int j = 0; j < 16; ++j) v0[j] = colp[(size_t)ra[j] * nw];
            u64 acc = 0;
            for (int base = 16; base < cp; base += 16) {
                int rb[16];
                #pragma unroll
                for (int j = 0; j < 16; ++j) rb[j] = s_list[base + j];
                u64 v1[16];
                #pragma unroll
                for (int j = 0; j < 16; ++j) v1[j] = colp[(size_t)rb[j] * nw];
                #pragma unroll
                for (int j = 0; j < 16; ++j) acc |= v0[j];   // waits vmcnt(16)
                #pragma unroll
                for (int j = 0; j < 16; ++j) v0[j] = v1[j];
            }
            #pragma unroll
            for (int j = 0; j < 16; ++j) acc |= v0[j];
            if (acc) atomicOr(&s_remv[w], acc);
        }

        // resolve: wave 0 (uniform, redundant across its 64 lanes)
        if (t < 64) {
            u64 c0 = s_remv[2 * b], c1 = s_remv[2 * b + 1];
            u64 kw0 = 0, kw1 = 0;
            int lim = n - b * 128;
            #pragma unroll
            for (int g = 0; g < 8; ++g) {
                ulonglong2 rr[8];
                #pragma unroll
                for (int j = 0; j < 8; ++j) rr[j] = sdA[c][g * 8 + j];
                #pragma unroll
                for (int j = 0; j < 8; ++j) {
                    int k = g * 8 + j;
                    if (k < lim && !((c0 >> k) & 1)) {
                        kw0 |= 1ULL << k;
                        c0 |= rr[j].x;
                        c1 |= rr[j].y;
                    }
                }
            }
            #pragma unroll
            for (int g = 0; g < 8; ++g) {
                u64 rr[8];
                #pragma unroll
                for (int j = 0; j < 8; ++j) rr[j] = sdB[c][g * 8 + j];
                #pragma unroll
                for (int j = 0; j < 8; ++j) {
                    int k = g * 8 + j;
                    if (k + 64 < lim && !((c1 >> k) & 1)) {
                        kw1 |= 1ULL << k;
                        c1 |= rr[j];
                    }
                }
            }
            if (t == 0) {
                s_kw[0] = kw0; s_kw[1] = kw1;
                keepw[2 * b] = kw0;
                if (2 * b + 1 < nw) keepw[2 * b + 1] = kw1;
            }
        }
        __syncthreads();

        // ================= phase 1 =================
        u64 kw0 = s_kw[0], kw1 = s_kw[1];
        if (t < 128) {
            bool kept = (t < 64) ? ((kw0 >> t) & 1) : ((kw1 >> (t - 64)) & 1);
            // near contribution: wave OR-reduce, 1 atomic per wave
            u64 a0 = kept ? sv0 : 0;
            u64 a1 = kept ? sv1 : 0;
            #pragma unroll
            for (int m = 1; m < 64; m <<= 1) {
                a0 |= shfl_xor_u64(a0, m);
                a1 |= shfl_xor_u64(a1, m);
            }
            if ((t & 63) == 0) {
                if (a0) atomicOr(&s_remv[2 * b + 2], a0);
                if (a1) atomicOr(&s_remv[2 * b + 3], a1);
            }
            // kept-list build (parallel prefix via popcount)
            int pos;
            if (t < 64) pos = __popcll(kw0 & ((t == 0) ? 0ULL : ((1ULL << t) - 1)));
            else        pos = __popcll(kw0) + __popcll(kw1 & ((1ULL << (t - 64)) - 1));
            if (kept) s_list[pos] = b * 128 + t;
            // stage next diag
            if (t < 64) sdA[c ^ 1][t] = make_ulonglong2(nd0, nd1);
            else        sdB[c ^ 1][t - 64] = nd1;
        }
        if (t == 128) {
            int cnt = __popcll(kw0) + __popcll(kw1);
            s_cnt = cnt;
            if (cnt > 0) {
                int last = kw1 ? (127 - __clzll(kw1)) : (63 - __clzll(kw0));
                int padrow = b * 128 + last;
                int cp = (cnt + 15) & ~15;
                for (int i = cnt; i < cp; ++i) s_list[i] = padrow;
            }
        }
        __syncthreads();
    }
}

// ---------------- K5: masked output -----------------------------------------
__global__ void out_kernel(const float* __restrict__ sbox, const float* __restrict__ sconf,
                           const u64* __restrict__ keepw, int n, float* __restrict__ out) {
    int e = blockIdx.x * 256 + threadIdx.x;
    if (e >= n * 5) return;
    int r = e / 5, c = e - r * 5;
    float keep = ((keepw[r >> 6] >> (r & 63)) & 1ULL) ? 1.0f : 0.0f;
    float v = (c < 4) ? sbox[r * 4 + c] : sconf[r];
    out[e] = v * keep;
}

extern "C" void kernel_launch(void* const* d_in, const int* in_sizes, int n_in,
                              void* d_out, int out_size, void* d_ws, size_t ws_size,
                              hipStream_t stream) {
    const float* yb = (const float*)d_in[0];
    const float* yc = (const float*)d_in[1];
    const float* db = (const float*)d_in[2];
    const float* dc = (const float*)d_in[3];
    int n1 = in_sizes[1];
    int n2 = in_sizes[3];
    int n  = n1 + n2;                          // 8700
    int nw = (n + 63) / 64;                    // 136

    char* w = (char*)d_ws;
    u64*    sup   = (u64*)w;                                   // MAXN*nw*8 ~ 9.47 MB
    u64*    band  = (u64*)(w + (size_t)MAXN * nw * 8);         // MAXN*4*8 = 278 KB
    float4* xyxy  = (float4*)(band + (size_t)MAXN * 4);
    float4* sbox  = xyxy + MAXN;
    float*  conf  = (float*)(sbox + MAXN);
    float*  sconf = conf + MAXN;
    u32*    key   = (u32*)(sconf + MAXN);
    int*    rank  = (int*)(key + MAXN);
    u64*    keepw = (u64*)(rank + MAXN);

    hipMemsetAsync(rank, 0, MAXN * sizeof(int), stream);
    hipMemsetAsync(band, 0, (size_t)MAXN * 4 * sizeof(u64), stream);

    int nb = (n + 255) / 256;                                  // 34
    prep_kernel<<<nb, 256, 0, stream>>>(yb, yc, db, dc, n1, n, xyxy, conf, key);

    dim3 g1(nb, (n + CHUNK - 1) / CHUNK);                      // 34 x 17
    rank_kernel<<<g1, 256, 0, stream>>>(key, n, rank);

    scatter_kernel<<<nb, 256, 0, stream>>>(xyxy, conf, rank, n, sbox, sconf);

    dim3 g3(nw, nw);                                           // 136 x 136
    iou_kernel<<<g3, 64, 0, stream>>>(sbox, n, nw, sup, band);

    scan_kernel<<<1, 256, 0, stream>>>(sup, band, n, nw, keepw);

    out_kernel<<<(n * 5 + 255) / 256, 256, 0, stream>>>((const float*)sbox, sconf,
                                                        keepw, n, (float*)d_out);
}